// Round 5
// baseline (437.354 us; speedup 1.0000x reference)
//
#include <hip/hip_runtime.h>
#include <stdint.h>

#define NUM_TOKENS 16384
#define DIM        4096
#define NEXP       256
#define MB         32      // tokens per block (grid = 512 -> 2+ blocks/CU)
#define BK         64      // K per staging step
#define NITER      (DIM / BK)
#define APAD       72      // A row stride (+8 kills bank conflicts, keeps 16B align)
#define NWAVES     4
#define MARGIN     0.025f  // ~8.6 sigma of the pure-bf16 gap error (std ~2.9e-3)
#define CAP        16384   // refinement list capacity

typedef __attribute__((ext_vector_type(4))) float   f32x4;
typedef __attribute__((ext_vector_type(8))) __bf16  bf16x8;
typedef __attribute__((ext_vector_type(8))) unsigned short u16x8;

static __device__ __forceinline__ unsigned short f32_to_bf16(float f) {
    unsigned int u = __float_as_uint(f);
    u += 0x7fffu + ((u >> 16) & 1u);     // round-to-nearest-even
    return (unsigned short)(u >> 16);
}

// ---------------------------------------------------------------- kernel 1
// Convert weight fp32 -> bf16; zero the refinement counter.
__global__ void cvt_weights(const float* __restrict__ w,
                            unsigned short* __restrict__ wh,
                            int* __restrict__ counter) {
    if (blockIdx.x == 0 && threadIdx.x == 0) *counter = 0;
    const int n4 = NEXP * DIM / 4;
    const int stride = gridDim.x * blockDim.x;
    for (int i = blockIdx.x * blockDim.x + threadIdx.x; i < n4; i += stride) {
        float4 v = ((const float4*)w)[i];
        ushort4 h;
        h.x = f32_to_bf16(v.x); h.y = f32_to_bf16(v.y);
        h.z = f32_to_bf16(v.z); h.w = f32_to_bf16(v.w);
        ((ushort4*)wh)[i] = h;
    }
}

// ---------------------------------------------------------------- kernel 2
// Fused bf16 GEMM + top-2: block = 32 tokens x 256 experts, full K.
// 256 thr / 4 waves; wave = 32 tokens x 64 experts (mt=2, nt=4).
// grid=512 -> 2+ blocks/CU; LDS ~39 KB so up to 4 co-resident: inter-block
// overlap hides the barrier vmcnt drain (intra-block dbuf proved useless, R3).
// B LDS uses an XOR chunk swizzle realized on the DMA source address.
__global__ __launch_bounds__(256, 4) void gate_main(
    const float* __restrict__ x,
    const unsigned short* __restrict__ wh,
    float* __restrict__ out,           // [0,T) weights, [T,2T) indices (as float)
    int* __restrict__ counter,
    int4* __restrict__ entries)
{
    __shared__ unsigned short lAh[MB][APAD];    // 4.5 KB
    __shared__ unsigned short lBh[NEXP * BK];   // 32 KB
    __shared__ float4 cand[NWAVES][MB];         // 2 KB

    const int tid  = threadIdx.x;
    const int wv   = tid >> 6;          // wave 0..3 -> experts [wv*64, wv*64+64)
    const int lane = tid & 63;
    const int tok0 = blockIdx.x * MB;

    // A staging: thread covers token ta, 8 floats at kseg
    const int ta   = tid >> 3;          // 0..31
    const int kseg = (tid & 7) * 8;     // 0..56
    const float* xrow = x + (size_t)(tok0 + ta) * DIM + kseg;

    // B staging coords (XOR-swizzled source chunk): lane l writes LDS chunk
    // (l&7) of expert base+(l>>3); slot holds global chunk ((l&7) ^ (e&7)).
    const int esub   = lane >> 3;                 // == e&7
    const int bk_off = ((lane & 7) ^ esub) * 8;   // swizzled source element offset

    const int quad = lane >> 4;
    const int col  = lane & 15;

    f32x4 acc[2][4];
    #pragma unroll
    for (int mt = 0; mt < 2; ++mt)
        #pragma unroll
        for (int nt = 0; nt < 4; ++nt)
            acc[mt][nt] = f32x4{0.f, 0.f, 0.f, 0.f};

    float4 xv0 = *(const float4*)(xrow);
    float4 xv1 = *(const float4*)(xrow + 4);

    for (int it = 0; it < NITER; ++it) {
        const int k0 = it * BK;

        // ---- stage B via async DMA (8 instrs/wave cover this wave's 64 experts)
        #pragma unroll
        for (int jj = 0; jj < 8; ++jj) {
            const int e = wv * 64 + jj * 8 + esub;
            const unsigned short* gh = wh + (size_t)e * DIM + k0 + bk_off;
            unsigned short* dh = &lBh[(wv * 64 + jj * 8) * BK]; // wave-uniform base
            __builtin_amdgcn_global_load_lds(
                (const __attribute__((address_space(1))) unsigned int*)gh,
                (__attribute__((address_space(3))) unsigned int*)dh, 16, 0, 0);
        }

        // ---- convert + store A (8 bf16/thread)
        {
            u16x8 h0;
            h0[0] = f32_to_bf16(xv0.x); h0[1] = f32_to_bf16(xv0.y);
            h0[2] = f32_to_bf16(xv0.z); h0[3] = f32_to_bf16(xv0.w);
            h0[4] = f32_to_bf16(xv1.x); h0[5] = f32_to_bf16(xv1.y);
            h0[6] = f32_to_bf16(xv1.z); h0[7] = f32_to_bf16(xv1.w);
            *(u16x8*)&lAh[ta][kseg] = h0;
        }
        __syncthreads();   // drains DMA + lds writes (compiler vmcnt/lgkm 0)

        // ---- prefetch next iteration's x during compute
        if (it + 1 < NITER) {
            xv0 = *(const float4*)(xrow + (it + 1) * BK);
            xv1 = *(const float4*)(xrow + (it + 1) * BK + 4);
        }

        // ---- compute: 2 k-subtiles of 32; 8 MFMAs each
        #pragma unroll
        for (int kk = 0; kk < BK; kk += 32) {
            const int kc = kk >> 3;               // chunk base: 0 or 4
            bf16x8 ah[2], bh[4];
            #pragma unroll
            for (int mt = 0; mt < 2; ++mt)
                ah[mt] = *(const bf16x8*)&lAh[mt * 16 + col][kk + quad * 8];
            #pragma unroll
            for (int nt = 0; nt < 4; ++nt) {
                const int e = wv * 64 + nt * 16 + col;
                const int cpos = (((kc + quad) ^ (col & 7)) * 8); // unswizzle (e&7==col&7)
                bh[nt] = *(const bf16x8*)&lBh[e * BK + cpos];
            }
            #pragma unroll
            for (int mt = 0; mt < 2; ++mt)
                #pragma unroll
                for (int nt = 0; nt < 4; ++nt)
                    acc[mt][nt] = __builtin_amdgcn_mfma_f32_16x16x32_bf16(
                        ah[mt], bh[nt], acc[mt][nt], 0, 0, 0);
        }
        __syncthreads();   // protect LDS reuse
    }

    // ---- epilogue: per-wave top-2 over its 64 experts, per token.
    // C/D layout (16x16): col = lane&15 (expert), row = quad*4 + reg (token).
    #pragma unroll
    for (int mt = 0; mt < 2; ++mt) {
        #pragma unroll
        for (int r = 0; r < 4; ++r) {
            // local top-2 across nt = 4 candidates
            float t1s = acc[mt][0][r]; int t1e = wv * 64 + col;
            float t2s = acc[mt][1][r]; int t2e = t1e + 16;
            if (t2s > t1s) { float ts = t1s; int te = t1e; t1s = t2s; t1e = t2e; t2s = ts; t2e = te; }
            #pragma unroll
            for (int nt = 2; nt < 4; ++nt) {
                float s = acc[mt][nt][r]; int e = wv * 64 + nt * 16 + col;
                if (s > t1s)      { t2s = t1s; t2e = t1e; t1s = s; t1e = e; }
                else if (s > t2s) { t2s = s; t2e = e; }
            }
            // quad-local shuffle reduce over the 16 cols (same token row)
            #pragma unroll
            for (int m = 1; m <= 8; m <<= 1) {
                float o1s = __shfl_xor(t1s, m); int o1e = __shfl_xor(t1e, m);
                float o2s = __shfl_xor(t2s, m); int o2e = __shfl_xor(t2e, m);
                bool o1_top = (o1s > t1s) || (o1s == t1s && o1e < t1e);
                if (o1_top) {
                    bool keep_t1 = (t1s > o2s) || (t1s == o2s && t1e < o2e);
                    t2s = keep_t1 ? t1s : o2s; t2e = keep_t1 ? t1e : o2e;
                    t1s = o1s; t1e = o1e;
                } else {
                    bool o1_2nd = (o1s > t2s) || (o1s == t2s && o1e < t2e);
                    if (o1_2nd) { t2s = o1s; t2e = o1e; }
                }
            }
            if (col == 0) {
                int tok = mt * 16 + quad * 4 + r;
                cand[wv][tok] = make_float4(t1s, __int_as_float(t1e), t2s, __int_as_float(t2e));
            }
        }
    }
    __syncthreads();

    // ---- final merge across waves; write outputs + near-tie flags
    if (tid < MB) {
        float4 c0 = cand[0][tid];
        float t1s = c0.x; int t1e = __float_as_int(c0.y);
        float t2s = c0.z; int t2e = __float_as_int(c0.w);
        #pragma unroll
        for (int wvi = 1; wvi < NWAVES; ++wvi) {
            float4 c = cand[wvi][tid];
            float o1s = c.x; int o1e = __float_as_int(c.y);
            float o2s = c.z; int o2e = __float_as_int(c.w);
            bool o1_top = (o1s > t1s) || (o1s == t1s && o1e < t1e);
            if (o1_top) {
                bool keep_t1 = (t1s > o2s) || (t1s == o2s && t1e < o2e);
                t2s = keep_t1 ? t1s : o2s; t2e = keep_t1 ? t1e : o2e;
                t1s = o1s; t1e = o1e;
            } else {
                bool o1_2nd = (o1s > t2s) || (o1s == t2s && o1e < t2e);
                if (o1_2nd) { t2s = o1s; t2e = o1e; }
            }
        }
        const int gtok = tok0 + tid;
        out[gtok] = 1.0f;                       // STE forward value at argmax
        out[NUM_TOKENS + gtok] = (float)t1e;    // index as float
        if (t1s - t2s < MARGIN) {
            int slot = atomicAdd(counter, 1);
            if (slot < CAP) entries[slot] = make_int4(gtok, t1e, t2e, 0);
        }
    }
}

// ---------------------------------------------------------------- kernel 3
// fp64 re-verification of near-tie tokens (one wave per flagged token).
__global__ void refine(const float* __restrict__ x,
                       const float* __restrict__ w,
                       const int* __restrict__ counter,
                       const int4* __restrict__ entries,
                       float* __restrict__ out) {
    const int gwave  = (blockIdx.x * blockDim.x + threadIdx.x) >> 6;
    const int lane   = threadIdx.x & 63;
    const int nwaves = (gridDim.x * blockDim.x) >> 6;
    int n = *counter; if (n > CAP) n = CAP;
    for (int i = gwave; i < n; i += nwaves) {
        int4 e = entries[i];
        const float* xr = x + (size_t)e.x * DIM;
        const float* w1 = w + (size_t)e.y * DIM;
        const float* w2 = w + (size_t)e.z * DIM;
        double d1 = 0.0, d2 = 0.0;
        for (int k = lane; k < DIM; k += 64) {
            double xv = (double)xr[k];
            d1 += xv * (double)w1[k];
            d2 += xv * (double)w2[k];
        }
        #pragma unroll
        for (int m = 32; m > 0; m >>= 1) {
            d1 += __shfl_xor(d1, m);
            d2 += __shfl_xor(d2, m);
        }
        if (lane == 0) {
            int best = (d1 > d2) ? e.y : ((d2 > d1) ? e.z : (e.y < e.z ? e.y : e.z));
            out[NUM_TOKENS + e.x] = (float)best;
        }
    }
}

// ---------------------------------------------------------------- launcher
extern "C" void kernel_launch(void* const* d_in, const int* in_sizes, int n_in,
                              void* d_out, int out_size, void* d_ws, size_t ws_size,
                              hipStream_t stream) {
    const float* x = (const float*)d_in[0];
    const float* w = (const float*)d_in[1];
    float* out = (float*)d_out;

    char* ws = (char*)d_ws;
    unsigned short* wh = (unsigned short*)ws;                     // 2 MB
    int*  counter = (int*)(ws + (2u << 20));
    int4* entries = (int4*)(ws + (2u << 20) + 16);                // 256 KB

    cvt_weights<<<256, 256, 0, stream>>>(w, wh, counter);
    gate_main<<<NUM_TOKENS / MB, 256, 0, stream>>>(x, wh, out, counter, entries);
    refine<<<256, 256, 0, stream>>>(x, w, counter, entries, out);
}

// Round 6
// 430.819 us; speedup vs baseline: 1.0152x; 1.0152x over previous
//
#include <hip/hip_runtime.h>
#include <stdint.h>

#define NUM_TOKENS 16384
#define DIM        4096
#define NEXP       256
#define MB         32      // tokens per block
#define BK         64      // K per staging step
#define NITER      (DIM / BK)
#define APAD       72      // A row stride (+8 kills bank conflicts, keeps 16B align)
#define NWAVES     8
#define MARGIN     0.025f  // ~8.6 sigma of the pure-bf16 gap error (std ~2.9e-3)
#define CAP        16384   // refinement list capacity

typedef __attribute__((ext_vector_type(4))) float   f32x4;
typedef __attribute__((ext_vector_type(8))) __bf16  bf16x8;

static __device__ __forceinline__ unsigned short f32_to_bf16(float f) {
    unsigned int u = __float_as_uint(f);
    u += 0x7fffu + ((u >> 16) & 1u);     // round-to-nearest-even
    return (unsigned short)(u >> 16);
}

// ---------------------------------------------------------------- kernel 1
// Convert weight fp32 -> bf16; zero the refinement counter.
__global__ void cvt_weights(const float* __restrict__ w,
                            unsigned short* __restrict__ wh,
                            int* __restrict__ counter) {
    if (blockIdx.x == 0 && threadIdx.x == 0) *counter = 0;
    const int n4 = NEXP * DIM / 4;
    const int stride = gridDim.x * blockDim.x;
    for (int i = blockIdx.x * blockDim.x + threadIdx.x; i < n4; i += stride) {
        float4 v = ((const float4*)w)[i];
        ushort4 h;
        h.x = f32_to_bf16(v.x); h.y = f32_to_bf16(v.y);
        h.z = f32_to_bf16(v.z); h.w = f32_to_bf16(v.w);
        ((ushort4*)wh)[i] = h;
    }
}

// ---------------------------------------------------------------- kernel 2
// Fused bf16 GEMM + top-2: block = 32 tokens x 256 experts, full K.
// 512 thr / 8 waves; wave = 32 tokens x 32 experts (mt=2, nt=2).
// grid=512, LDS 40.5 KB -> 2 blocks/CU = 16 waves/CU = 4 waves/SIMD:
// this is the round's one change — R2..R5 all ran 2 waves/SIMD and were
// latency-starved (ds_read ~120cyc chains uncovered; m97 needed 3/SIMD).
// B LDS uses an XOR chunk swizzle realized on the DMA source address.
__global__ __launch_bounds__(512, 4) void gate_main(
    const float* __restrict__ x,
    const unsigned short* __restrict__ wh,
    float* __restrict__ out,           // [0,T) weights, [T,2T) indices (as float)
    int* __restrict__ counter,
    int4* __restrict__ entries)
{
    __shared__ unsigned short lAh[MB][APAD];    // 4.5 KB
    __shared__ unsigned short lBh[NEXP * BK];   // 32 KB
    __shared__ float4 cand[NWAVES][MB];         // 4 KB

    const int tid  = threadIdx.x;
    const int wv   = tid >> 6;          // wave 0..7 -> experts [wv*32, wv*32+32)
    const int lane = tid & 63;
    const int tok0 = blockIdx.x * MB;

    // A staging: thread covers token ta, 4 floats at kcol
    const int ta   = tid >> 4;          // 0..31
    const int kcol = (tid & 15) * 4;    // 0..60
    const float* xrow = x + (size_t)(tok0 + ta) * DIM + kcol;

    // B staging coords (XOR-swizzled source chunk): lane l writes LDS chunk
    // (l&7) of expert base+(l>>3); slot holds global chunk ((l&7) ^ (e&7)).
    const int esub   = lane >> 3;                 // == e&7
    const int bk_off = ((lane & 7) ^ esub) * 8;   // swizzled source element offset

    const int quad = lane >> 4;
    const int col  = lane & 15;

    f32x4 acc[2][2];
    #pragma unroll
    for (int mt = 0; mt < 2; ++mt)
        #pragma unroll
        for (int nt = 0; nt < 2; ++nt)
            acc[mt][nt] = f32x4{0.f, 0.f, 0.f, 0.f};

    float4 xv = *(const float4*)(xrow);

    for (int it = 0; it < NITER; ++it) {
        const int k0 = it * BK;

        // ---- stage B via async DMA (4 instrs/wave cover this wave's 32 experts)
        #pragma unroll
        for (int jj = 0; jj < 4; ++jj) {
            const int e = wv * 32 + jj * 8 + esub;
            const unsigned short* gh = wh + (size_t)e * DIM + k0 + bk_off;
            unsigned short* dh = &lBh[(wv * 32 + jj * 8) * BK]; // wave-uniform base
            __builtin_amdgcn_global_load_lds(
                (const __attribute__((address_space(1))) unsigned int*)gh,
                (__attribute__((address_space(3))) unsigned int*)dh, 16, 0, 0);
        }

        // ---- convert + store A (4 bf16/thread, 8B LDS write)
        {
            ushort4 h;
            h.x = f32_to_bf16(xv.x); h.y = f32_to_bf16(xv.y);
            h.z = f32_to_bf16(xv.z); h.w = f32_to_bf16(xv.w);
            *(ushort4*)&lAh[ta][kcol] = h;
        }
        __syncthreads();   // drains DMA + lds writes (compiler vmcnt/lgkm 0)

        // ---- prefetch next iteration's x during compute
        if (it + 1 < NITER) {
            xv = *(const float4*)(xrow + (it + 1) * BK);
        }

        // ---- compute: 2 k-subtiles of 32; 4 MFMAs each
        #pragma unroll
        for (int kk = 0; kk < BK; kk += 32) {
            const int kc = kk >> 3;               // chunk base: 0 or 4
            bf16x8 ah[2], bh[2];
            #pragma unroll
            for (int mt = 0; mt < 2; ++mt)
                ah[mt] = *(const bf16x8*)&lAh[mt * 16 + col][kk + quad * 8];
            #pragma unroll
            for (int nt = 0; nt < 2; ++nt) {
                const int e = wv * 32 + nt * 16 + col;
                const int cpos = (((kc + quad) ^ (col & 7)) * 8); // unswizzle (e&7==col&7)
                bh[nt] = *(const bf16x8*)&lBh[e * BK + cpos];
            }
            #pragma unroll
            for (int mt = 0; mt < 2; ++mt)
                #pragma unroll
                for (int nt = 0; nt < 2; ++nt)
                    acc[mt][nt] = __builtin_amdgcn_mfma_f32_16x16x32_bf16(
                        ah[mt], bh[nt], acc[mt][nt], 0, 0, 0);
        }
        __syncthreads();   // protect LDS reuse
    }

    // ---- epilogue: per-wave top-2 over its 32 experts, per token.
    // C/D layout (16x16): col = lane&15 (expert), row = quad*4 + reg (token).
    #pragma unroll
    for (int mt = 0; mt < 2; ++mt) {
        #pragma unroll
        for (int r = 0; r < 4; ++r) {
            float s0 = acc[mt][0][r]; int e0 = wv * 32 + col;
            float s1 = acc[mt][1][r]; int e1 = e0 + 16;
            float t1s, t2s; int t1e, t2e;
            if (s1 > s0) { t1s = s1; t1e = e1; t2s = s0; t2e = e0; }
            else         { t1s = s0; t1e = e0; t2s = s1; t2e = e1; }
            #pragma unroll
            for (int m = 1; m <= 8; m <<= 1) {
                float o1s = __shfl_xor(t1s, m); int o1e = __shfl_xor(t1e, m);
                float o2s = __shfl_xor(t2s, m); int o2e = __shfl_xor(t2e, m);
                bool o1_top = (o1s > t1s) || (o1s == t1s && o1e < t1e);
                if (o1_top) {
                    bool keep_t1 = (t1s > o2s) || (t1s == o2s && t1e < o2e);
                    t2s = keep_t1 ? t1s : o2s; t2e = keep_t1 ? t1e : o2e;
                    t1s = o1s; t1e = o1e;
                } else {
                    bool o1_2nd = (o1s > t2s) || (o1s == t2s && o1e < t2e);
                    if (o1_2nd) { t2s = o1s; t2e = o1e; }
                }
            }
            if (col == 0) {
                int tok = mt * 16 + quad * 4 + r;
                cand[wv][tok] = make_float4(t1s, __int_as_float(t1e), t2s, __int_as_float(t2e));
            }
        }
    }
    __syncthreads();

    // ---- final merge across waves; write outputs + near-tie flags
    if (tid < MB) {
        float4 c0 = cand[0][tid];
        float t1s = c0.x; int t1e = __float_as_int(c0.y);
        float t2s = c0.z; int t2e = __float_as_int(c0.w);
        #pragma unroll
        for (int wvi = 1; wvi < NWAVES; ++wvi) {
            float4 c = cand[wvi][tid];
            float o1s = c.x; int o1e = __float_as_int(c.y);
            float o2s = c.z; int o2e = __float_as_int(c.w);
            bool o1_top = (o1s > t1s) || (o1s == t1s && o1e < t1e);
            if (o1_top) {
                bool keep_t1 = (t1s > o2s) || (t1s == o2s && t1e < o2e);
                t2s = keep_t1 ? t1s : o2s; t2e = keep_t1 ? t1e : o2e;
                t1s = o1s; t1e = o1e;
            } else {
                bool o1_2nd = (o1s > t2s) || (o1s == t2s && o1e < t2e);
                if (o1_2nd) { t2s = o1s; t2e = o1e; }
            }
        }
        const int gtok = tok0 + tid;
        out[gtok] = 1.0f;                       // STE forward value at argmax
        out[NUM_TOKENS + gtok] = (float)t1e;    // index as float
        if (t1s - t2s < MARGIN) {
            int slot = atomicAdd(counter, 1);
            if (slot < CAP) entries[slot] = make_int4(gtok, t1e, t2e, 0);
        }
    }
}

// ---------------------------------------------------------------- kernel 3
// fp64 re-verification of near-tie tokens (one wave per flagged token).
__global__ void refine(const float* __restrict__ x,
                       const float* __restrict__ w,
                       const int* __restrict__ counter,
                       const int4* __restrict__ entries,
                       float* __restrict__ out) {
    const int gwave  = (blockIdx.x * blockDim.x + threadIdx.x) >> 6;
    const int lane   = threadIdx.x & 63;
    const int nwaves = (gridDim.x * blockDim.x) >> 6;
    int n = *counter; if (n > CAP) n = CAP;
    for (int i = gwave; i < n; i += nwaves) {
        int4 e = entries[i];
        const float* xr = x + (size_t)e.x * DIM;
        const float* w1 = w + (size_t)e.y * DIM;
        const float* w2 = w + (size_t)e.z * DIM;
        double d1 = 0.0, d2 = 0.0;
        for (int k = lane; k < DIM; k += 64) {
            double xv = (double)xr[k];
            d1 += xv * (double)w1[k];
            d2 += xv * (double)w2[k];
        }
        #pragma unroll
        for (int m = 32; m > 0; m >>= 1) {
            d1 += __shfl_xor(d1, m);
            d2 += __shfl_xor(d2, m);
        }
        if (lane == 0) {
            int best = (d1 > d2) ? e.y : ((d2 > d1) ? e.z : (e.y < e.z ? e.y : e.z));
            out[NUM_TOKENS + e.x] = (float)best;
        }
    }
}

// ---------------------------------------------------------------- launcher
extern "C" void kernel_launch(void* const* d_in, const int* in_sizes, int n_in,
                              void* d_out, int out_size, void* d_ws, size_t ws_size,
                              hipStream_t stream) {
    const float* x = (const float*)d_in[0];
    const float* w = (const float*)d_in[1];
    float* out = (float*)d_out;

    char* ws = (char*)d_ws;
    unsigned short* wh = (unsigned short*)ws;                     // 2 MB
    int*  counter = (int*)(ws + (2u << 20));
    int4* entries = (int4*)(ws + (2u << 20) + 16);                // 256 KB

    cvt_weights<<<256, 256, 0, stream>>>(w, wh, counter);
    gate_main<<<NUM_TOKENS / MB, 512, 0, stream>>>(x, wh, out, counter, entries);
    refine<<<256, 256, 0, stream>>>(x, w, counter, entries, out);
}